// Round 7
// baseline (27.530 us; speedup 1.0000x reference)
//
#include <hip/hip_runtime.h>

#define B 16
#define T 2048
#define D 1024
#define NSLICE 32            // column slices (32 floats each)
#define NJ 32                // equal-work row chunks per slice
#define SLICE (D / NSLICE)   // 32 floats = 8 float4

#define FMA4(c, v, a)                    \
    do {                                 \
        (a).x = fmaf((c), (v).x, (a).x); \
        (a).y = fmaf((c), (v).y, (a).y); \
        (a).z = fmaf((c), (v).z, (a).z); \
        (a).w = fmaf((c), (v).w, (a).w); \
    } while (0)

// Equal-work single kernel. Work is indexed in the CONCATENATED active-row
// space (N = sum(len)): block (slice s, chunk j) streams global rows
// [j*W, (j+1)*W), W = ceil(N/32) — identical load per block regardless of
// the length distribution (fixes R6's fixed-pair makespan skew: max pair
// len[i]+len[i+8] ~ 3500 rows -> 18 us; now every CU gets 4 equal blocks).
// At each batch boundary inside its range the block LDS-reduces its 32
// partial floats and atomicAdds them to out (~49K atomics total on 16K
// addresses — negligible; R2's poison was 1M-on-16K). out is zeroed by
// hipMemsetAsync (capture-safe, the harness itself uses it).
__global__ __launch_bounds__(256, 4) void fused_bal_kernel(
    const float* __restrict__ input,
    const int* __restrict__ lengths,
    const float* __restrict__ weights,
    float* __restrict__ out) {
    const int s   = blockIdx.x & (NSLICE - 1);
    const int j   = blockIdx.x >> 5;
    const int tid = threadIdx.x;
    const int c   = tid & 7;    // float4 column within slice
    const int rp  = tid >> 3;   // row phase 0..31

    // batch extents (redundant per thread; lengths is 64B, L2-hot)
    int st[B], ln[B];
    int N = 0;
#pragma unroll
    for (int i = 0; i < B; ++i) {
        ln[i] = lengths[i];
        st[i] = N;
        N += ln[i];
    }
    const int W  = (N + NJ - 1) >> 5;
    const int g0 = j * W;
    const int g1 = min(g0 + W, N);
    if (g0 >= g1) return;

    // softmax denominator (unnormalized exp coeffs; weights~N(0,1) so no
    // overflow without max-subtraction). 8 expf/thread, VALU is idle anyway.
    float lsum = 0.f;
#pragma unroll
    for (int i = 0; i < 8; ++i)
        lsum += expf(weights[tid * 8 + i]);
#pragma unroll
    for (int off = 32; off > 0; off >>= 1)
        lsum += __shfl_xor(lsum, off);
    __shared__ float red[4];
    if ((tid & 63) == 0) red[tid >> 6] = lsum;
    __syncthreads();
    const float inv = 1.f / (red[0] + red[1] + red[2] + red[3]);

    __shared__ float4 lds[32][8];

    int g = g0;
#pragma unroll 1
    for (int i = 0; i < B; ++i) {
        if (g >= g1) break;
        if (g >= st[i] + ln[i]) continue;   // batch fully before our range
        const int t0 = g - st[i];
        const int t1 = min(g1 - st[i], ln[i]);

        const float4* __restrict__ in4 =
            (const float4*)input + (size_t)i * T * (D / 4) + s * (SLICE / 4) + c;

        float4 acc = make_float4(0.f, 0.f, 0.f, 0.f);
#pragma unroll 4
        for (int t = t0 + rp; t < t1; t += 32) {
            const float  cw = expf(weights[t]);   // L1-hot 8KB table
            const float4 v  = in4[(size_t)t * (D / 4)];
            FMA4(cw, v, acc);
        }

        // tree-reduce the 32 row phases -> 32 floats, flush to out
        lds[rp][c] = acc;
        __syncthreads();
#pragma unroll
        for (int off = 16; off > 0; off >>= 1) {
            if (rp < off) {
                const float4 o = lds[rp + off][c];
                acc.x += o.x; acc.y += o.y; acc.z += o.z; acc.w += o.w;
                lds[rp][c] = acc;
            }
            __syncthreads();
        }
        if (tid < SLICE) {   // lds[0][0..7] = 32 contiguous floats
            const float val = ((const float*)&lds[0][0])[tid];
            atomicAdd(&out[i * D + s * SLICE + tid], val * inv);
        }
        __syncthreads();     // protect LDS reuse by next segment

        g = st[i] + t1;
    }
}

extern "C" void kernel_launch(void* const* d_in, const int* in_sizes, int n_in,
                              void* d_out, int out_size, void* d_ws, size_t ws_size,
                              hipStream_t stream) {
    const float* input   = (const float*)d_in[0];
    const int*   lengths = (const int*)d_in[1];
    const float* weights = (const float*)d_in[2];
    float* out = (float*)d_out;

    hipMemsetAsync(out, 0, (size_t)out_size * sizeof(float), stream);
    fused_bal_kernel<<<NSLICE * NJ, 256, 0, stream>>>(input, lengths, weights, out);
}

// Round 8
// 18.227 us; speedup vs baseline: 1.5104x; 1.5104x over previous
//
#include <hip/hip_runtime.h>

#define B 16
#define T 2048
#define D 1024
#define NSLICE 32            // slice-blocks per batch
#define SLICE (D / NSLICE)   // 32 floats = 8 float4 per block

#define FMA4(c, v, a)                    \
    do {                                 \
        (a).x = fmaf((c), (v).x, (a).x); \
        (a).y = fmaf((c), (v).y, (a).y); \
        (a).z = fmaf((c), (v).z, (a).z); \
        (a).w = fmaf((c), (v).w, (a).w); \
    } while (0)

// R6 structure (single kernel, slice-columns, single-writer stores, no
// atomics/fences/scratch/memset) + length-sorted batch pairing.
// CU k hosts blocks k and k+256 -> slots q and q+8 (true under linear AND
// XCD-round-robin dispatch). Mapping slot->batch via the length-sorted
// order pairs rank q with rank 15-q (longest with shortest), so per-CU
// work ~ N/16 regardless of the length skew that limited R6
// (max len[i]+len[i+8] ~ 3500 rows ~ 18us).
// Sort = fully-unrolled odd-even transposition on packed (len<<4|idx)
// keys: all array indices compile-time (no local-memory spill).
// Coefficients exp(w[t]) are precomputed into LDS (8KB) once per block:
// the stream loop does 1 ds_read + 1 global float4 + 4 fmac per row.
__global__ __launch_bounds__(256, 4) void fused2_kernel(
    const float* __restrict__ input,
    const int* __restrict__ lengths,
    const float* __restrict__ weights,
    float* __restrict__ out) {
    const int j   = blockIdx.x >> 5;   // batch slot 0..15
    const int s   = blockIdx.x & 31;   // slice
    const int tid = threadIdx.x;
    const int c   = tid & 7;           // float4 column within slice
    const int rp  = tid >> 3;          // row phase 0..31

    // ---- sorted batch pairing (uniform, compile-time-indexed) ----
    unsigned key[B];
#pragma unroll
    for (int i = 0; i < B; ++i)
        key[i] = ((unsigned)lengths[i] << 4) | (unsigned)i;
#pragma unroll
    for (int pass = 0; pass < B; ++pass) {
#pragma unroll
        for (int i = (pass & 1); i + 1 < B; i += 2) {
            const unsigned a = key[i], b2 = key[i + 1];
            if (a < b2) { key[i] = b2; key[i + 1] = a; }   // descending
        }
    }
    const unsigned k = (j < 8) ? key[j] : key[23 - j];     // rank j / 15-(j-8)
    const int b   = (int)(k & 15u);
    const int len = (int)(k >> 4);

    // ---- coeff table exp(w) -> LDS; denominator from the same values ----
    __shared__ float cf[T];            // 8 KB
    __shared__ float red[4];
    float lsum = 0.f;
#pragma unroll
    for (int i = 0; i < 8; ++i) {
        const float e = expf(weights[tid * 8 + i]);
        cf[tid * 8 + i] = e;
        lsum += e;
    }
#pragma unroll
    for (int off = 32; off > 0; off >>= 1)
        lsum += __shfl_xor(lsum, off);
    if ((tid & 63) == 0) red[tid >> 6] = lsum;
    __syncthreads();
    const float inv = 1.f / (red[0] + red[1] + red[2] + red[3]);

    const float4* __restrict__ in4 =
        (const float4*)input + (size_t)b * T * (D / 4) + s * (SLICE / 4) + c;

    float4 acc = make_float4(0.f, 0.f, 0.f, 0.f);

    // full 32-row groups (uniform trip count)
    const int nfull = len >> 5;
    const float4* p = in4 + (size_t)rp * (D / 4);
#pragma unroll 4
    for (int it = 0; it < nfull; ++it) {
        const float  cw = cf[it * 32 + rp];
        const float4 v  = p[(size_t)it * 32 * (D / 4)];
        FMA4(cw, v, acc);
    }
    // tail rows
    const int r = (nfull << 5) + rp;
    if (r < len) {
        const float  cw = cf[r];
        const float4 v  = in4[(size_t)r * (D / 4)];
        FMA4(cw, v, acc);
    }

    // ---- LDS tree-reduce over the 32 row-phases ----
    __shared__ float4 lds[32][8];
    lds[rp][c] = acc;
    __syncthreads();
#pragma unroll
    for (int off = 16; off > 0; off >>= 1) {
        if (rp < off) {
            const float4 o = lds[rp + off][c];
            acc.x += o.x; acc.y += o.y; acc.z += o.z; acc.w += o.w;
            lds[rp][c] = acc;
        }
        __syncthreads();
    }

    if (tid < 8) {   // rp==0, c==tid: single writer of out[b, s*32+...]
        const float4 r4 = make_float4(acc.x * inv, acc.y * inv,
                                      acc.z * inv, acc.w * inv);
        ((float4*)out)[b * (D / 4) + s * (SLICE / 4) + tid] = r4;
    }
}

extern "C" void kernel_launch(void* const* d_in, const int* in_sizes, int n_in,
                              void* d_out, int out_size, void* d_ws, size_t ws_size,
                              hipStream_t stream) {
    const float* input   = (const float*)d_in[0];
    const int*   lengths = (const int*)d_in[1];
    const float* weights = (const float*)d_in[2];
    float* out = (float*)d_out;

    fused2_kernel<<<B * NSLICE, 256, 0, stream>>>(input, lengths, weights, out);
}